// Round 3
// baseline (335.998 us; speedup 1.0000x reference)
//
#include <hip/hip_runtime.h>
#include <cstdint>
#include <cstddef>

typedef __bf16 bf16;
typedef __bf16 bf16x8 __attribute__((ext_vector_type(8)));
typedef __bf16 bf16x4 __attribute__((ext_vector_type(4)));
typedef float f32x4 __attribute__((ext_vector_type(4)));
typedef float f32x16 __attribute__((ext_vector_type(16)));

#define LAMBDA_INIT_F 0.5560582041556405f
#define ONE_MINUS_LI_F 0.4439417958443595f

static constexpr int T = 2048;
static constexpr int ROWQ = 6144;  // q1|q2|k1|k2|v(2048)
// P = exp(s/8 - 16) = exp2(s*C1 + C0)
#define C1_EXP2 0.18033688011116027f
#define C0_EXP2 -23.083120654223414f

__device__ __forceinline__ f32x4 mfma16(bf16x8 a, bf16x8 b, f32x4 c) {
  return __builtin_amdgcn_mfma_f32_16x16x32_bf16(a, b, c, 0, 0, 0);
}
__device__ __forceinline__ f32x16 mfma32(bf16x8 a, bf16x8 b, f32x16 c) {
  return __builtin_amdgcn_mfma_f32_32x32x16_bf16(a, b, c, 0, 0, 0);
}

__device__ __forceinline__ void gld16(const bf16* g, bf16* l) {
  __builtin_amdgcn_global_load_lds(
      (const __attribute__((address_space(1))) void*)g,
      (__attribute__((address_space(3))) void*)l, 16, 0, 0);
}

__device__ __forceinline__ unsigned pk2(float a, float b) {
  unsigned short ua = __builtin_bit_cast(unsigned short, (bf16)a);
  unsigned short ub = __builtin_bit_cast(unsigned short, (bf16)b);
  return (unsigned)ua | ((unsigned)ub << 16);
}
__device__ __forceinline__ bf16x8 mk8(unsigned a, unsigned b, unsigned c, unsigned d) {
  union { unsigned u[4]; bf16x8 v; } t;
  t.u[0] = a; t.u[1] = b; t.u[2] = c; t.u[3] = d;
  return t.v;
}

// ---------------- conversion kernels ----------------

__global__ void cvt_f32_bf16(const float* __restrict__ src, bf16* __restrict__ dst, int n4) {
  int i = blockIdx.x * blockDim.x + threadIdx.x;
  if (i < n4) {
    float4 v = reinterpret_cast<const float4*>(src)[i];
    bf16x4 o;
    o[0] = (bf16)v.x; o[1] = (bf16)v.y; o[2] = (bf16)v.z; o[3] = (bf16)v.w;
    reinterpret_cast<bf16x4*>(dst)[i] = o;
  }
}

// src [K][N] f32 -> dst [N][K] bf16
__global__ void transpose_cvt(const float* __restrict__ src, bf16* __restrict__ dst,
                              int K, int N) {
  __shared__ float t[32][33];
  int tx = threadIdx.x, ty = threadIdx.y;
  int n0 = blockIdx.x * 32, k0 = blockIdx.y * 32;
#pragma unroll
  for (int j = 0; j < 32; j += 8)
    t[ty + j][tx] = src[(size_t)(k0 + ty + j) * N + n0 + tx];
  __syncthreads();
#pragma unroll
  for (int j = 0; j < 32; j += 8)
    dst[(size_t)(n0 + ty + j) * K + k0 + tx] = (bf16)t[tx][ty + j];
}

// V part of qkv -> Vt[bh][d=128][t=2048]
__global__ void vtrans(const bf16* __restrict__ qkv, bf16* __restrict__ Vt) {
  __shared__ bf16 tile[64][72];
  const int tid = threadIdx.x;
  const int t0 = blockIdx.x * 64, dt = blockIdx.y, bh = blockIdx.z;
  const int b = bh >> 4, h = bh & 15;
#pragma unroll
  for (int i = 0; i < 2; ++i) {
    int S = tid + i * 256;
    int r = S >> 3, c = S & 7;
    *reinterpret_cast<bf16x8*>(&tile[r][c * 8]) =
        *reinterpret_cast<const bf16x8*>(
            &qkv[(size_t)(b * T + t0 + r) * ROWQ + 4096 + h * 128 + dt * 64 + c * 8]);
  }
  __syncthreads();
#pragma unroll
  for (int i = 0; i < 2; ++i) {
    int S = tid + i * 256;
    int dr = S >> 3, tc = S & 7;
    bf16x8 v;
#pragma unroll
    for (int j = 0; j < 8; ++j) v[j] = tile[tc * 8 + j][dr];
    *reinterpret_cast<bf16x8*>(
        &Vt[((size_t)bh * 128 + dt * 64 + dr) * 2048 + t0 + tc * 8]) = v;
  }
}

// ---------------- GEMM: A[M,K] x Bt[N,K] -> C[M,N], BK=64, dbuf, gload_lds ----------------

template <typename OutT>
__global__ __launch_bounds__(256, 2) void gemm_bt(const bf16* __restrict__ A,
                                                  const bf16* __restrict__ Bt,
                                                  OutT* __restrict__ C,
                                                  int M, int N, int K) {
  __shared__ __align__(16) bf16 As[2][128 * 64];
  __shared__ __align__(16) bf16 Bs[2][128 * 64];
  const int tid = threadIdx.x;
  const int lane = tid & 63;
  const int wv = tid >> 6;
  const int wr = wv >> 1, wc = wv & 1;
  const int bm = blockIdx.y * 128, bn = blockIdx.x * 128;
  const int lr = lane & 15, lg = lane >> 4;

  f32x4 acc[4][4] = {};
  const int KT = K >> 6;

#define STAGE_AB(buf, kk0)                                                      \
  do {                                                                          \
    _Pragma("unroll") for (int i_ = 0; i_ < 4; ++i_) {                          \
      int S_ = (i_ * 4 + wv) * 64 + lane;                                       \
      int rw_ = S_ >> 3;                                                        \
      int cg_ = (S_ & 7) ^ (rw_ & 7);                                           \
      gld16(&A[(size_t)(bm + rw_) * K + (kk0) + cg_ * 8], &As[buf][(i_ * 4 + wv) * 512]); \
      gld16(&Bt[(size_t)(bn + rw_) * K + (kk0) + cg_ * 8], &Bs[buf][(i_ * 4 + wv) * 512]); \
    }                                                                           \
  } while (0)

  STAGE_AB(0, 0);
  for (int kt = 0; kt < KT; ++kt) {
    const int cur = kt & 1;
    asm volatile("s_waitcnt vmcnt(0)" ::: "memory");
    __syncthreads();
    if (kt + 1 < KT) STAGE_AB(cur ^ 1, (kt + 1) * 64);
#pragma unroll
    for (int kh = 0; kh < 2; ++kh) {
      bf16x8 af[4], bfr[4];
#pragma unroll
      for (int m = 0; m < 4; ++m)
        af[m] = *reinterpret_cast<const bf16x8*>(
            &As[cur][(wr * 64 + m * 16 + lr) * 64 + (((kh * 4 + lg) ^ (lr & 7)) * 8)]);
#pragma unroll
      for (int n = 0; n < 4; ++n)
        bfr[n] = *reinterpret_cast<const bf16x8*>(
            &Bs[cur][(wc * 64 + n * 16 + lr) * 64 + (((kh * 4 + lg) ^ (lr & 7)) * 8)]);
#pragma unroll
      for (int m = 0; m < 4; ++m)
#pragma unroll
        for (int n = 0; n < 4; ++n)
          acc[m][n] = mfma16(af[m], bfr[n], acc[m][n]);
    }
  }
#undef STAGE_AB

#pragma unroll
  for (int m = 0; m < 4; ++m)
#pragma unroll
    for (int n = 0; n < 4; ++n)
#pragma unroll
      for (int r = 0; r < 4; ++r) {
        int row = bm + wr * 64 + m * 16 + lg * 4 + r;
        int col = bn + wc * 64 + n * 16 + lr;
        C[(size_t)row * N + col] = (OutT)acc[m][n][r];
      }
}

// ---------------- differential flash attention + per-head LayerNorm ----------------
// 32x32x16 MFMA, swapped QK^T, in-register P via pack+shfl.
// grid (16, 32). waves 0,1: tile A (q-halves); waves 2,3: tile B.

__global__ __launch_bounds__(256, 2) void diff_attn(const bf16* __restrict__ qkv,
                                                    const bf16* __restrict__ Vtg,
                                                    const float* __restrict__ lq1,
                                                    const float* __restrict__ lk1,
                                                    const float* __restrict__ lq2,
                                                    const float* __restrict__ lk2,
                                                    bf16* __restrict__ yln) {
  __shared__ __align__(16) bf16 K1s[2][64 * 64];
  __shared__ __align__(16) bf16 K2s[2][64 * 64];
  __shared__ __align__(16) bf16 Vs[2][128 * 64];

  const int x = blockIdx.x;
  const int bh = blockIdx.y;
  const int b = bh >> 4, h = bh & 15;
  const int tid = threadIdx.x, lane = tid & 63, wv = tid >> 6;
  const int lc = lane & 31, hi = lane >> 5;

  const int u = b ? x : 15 - x;          // constant-sum pairing across co-resident blocks
  const int qtA = 31 - u, qtB = u;
  const int qt_w = (wv < 2) ? qtA : qtB;
  const int qbase = qt_w * 64 + (wv & 1) * 32;

  const int q1c = h * 64;
  const int q2c = 1024 + h * 64;
  const int k1c = 2048 + h * 64;
  const int k2c = 3072 + h * 64;

  // lambda (wave-parallel dot over 64)
  float a1 = lq1[h * 64 + lane] * lk1[h * 64 + lane];
  float a2 = lq2[h * 64 + lane] * lk2[h * 64 + lane];
#pragma unroll
  for (int m = 32; m >= 1; m >>= 1) {
    a1 += __shfl_xor(a1, m);
    a2 += __shfl_xor(a2, m);
  }
  const float lam = __expf(a1) - __expf(a2) + LAMBDA_INIT_F;

  // Q fragments (B-operand): lane holds Q[q=lc][d = kc*16 + hi*8 + j]
  bf16x8 q1f[4], q2f[4];
  {
    const bf16* qrow = qkv + (size_t)(b * T + qbase + lc) * ROWQ;
#pragma unroll
    for (int kc = 0; kc < 4; ++kc) {
      q1f[kc] = *reinterpret_cast<const bf16x8*>(qrow + q1c + kc * 16 + hi * 8);
      q2f[kc] = *reinterpret_cast<const bf16x8*>(qrow + q2c + kc * 16 + hi * 8);
    }
  }

  f32x16 o1[4] = {}, o2[4] = {};
  float l1 = 0.f, l2 = 0.f;

#define STAGE_KV(buf, tt0)                                                       \
  do {                                                                           \
    const bf16* kb_ = qkv + (size_t)(b * T + (tt0)) * ROWQ;                      \
    _Pragma("unroll") for (int i_ = 0; i_ < 2; ++i_) {                           \
      int S_ = (i_ * 4 + wv) * 64 + lane;                                        \
      int rw_ = S_ >> 3;                                                         \
      int cg_ = (S_ & 7) ^ (rw_ & 7);                                            \
      gld16(kb_ + (size_t)rw_ * ROWQ + k1c + cg_ * 8, &K1s[buf][(i_ * 4 + wv) * 512]); \
      gld16(kb_ + (size_t)rw_ * ROWQ + k2c + cg_ * 8, &K2s[buf][(i_ * 4 + wv) * 512]); \
    }                                                                            \
    _Pragma("unroll") for (int i_ = 0; i_ < 4; ++i_) {                           \
      int S_ = (i_ * 4 + wv) * 64 + lane;                                        \
      int dd_ = S_ >> 3;                                                         \
      int cg_ = (S_ & 7) ^ (dd_ & 7);                                            \
      gld16(Vtg + ((size_t)bh * 128 + dd_) * 2048 + (tt0) + cg_ * 8,             \
            &Vs[buf][(i_ * 4 + wv) * 512]);                                      \
    }                                                                            \
  } while (0)

  // QK^T (swapped: A=K rows, B=Q cols) for one att branch; exp; pack P frags.
#define QK_MAT(Ks, qf, pa, lacc)                                                 \
  do {                                                                           \
    f32x16 s0 = {}, s1 = {};                                                     \
    _Pragma("unroll") for (int kc = 0; kc < 4; ++kc) {                           \
      int g_ = (((kc * 2 + hi) ^ (lc & 7)) * 8);                                 \
      bf16x8 kf0 = *reinterpret_cast<const bf16x8*>(&Ks[cur][lc * 64 + g_]);     \
      bf16x8 kf1 = *reinterpret_cast<const bf16x8*>(&Ks[cur][(32 + lc) * 64 + g_]); \
      s0 = mfma32(kf0, qf[kc], s0);                                              \
      s1 = mfma32(kf1, qf[kc], s1);                                              \
    }                                                                            \
    const int qq_ = qbase + lc;                                                  \
    _Pragma("unroll") for (int r = 0; r < 16; ++r) {                             \
      int kl_ = kt * 64 + (r & 3) + 8 * (r >> 2) + 4 * hi;                       \
      float e0 = fmaf(s0[r], C1_EXP2, C0_EXP2);                                  \
      float e1 = fmaf(s1[r], C1_EXP2, C0_EXP2);                                  \
      if (edge) {                                                                \
        if (kl_ > qq_) e0 = -10000.f;                                            \
        if (kl_ + 32 > qq_) e1 = -10000.f;                                       \
      }                                                                          \
      s0[r] = exp2f(e0);                                                         \
      s1[r] = exp2f(e1);                                                         \
      lacc += s0[r] + s1[r];                                                     \
    }                                                                            \
    _Pragma("unroll") for (int kc = 0; kc < 4; ++kc) {                           \
      int base = 8 * (kc & 1);                                                   \
      float v0 = (kc < 2) ? s0[base + 0] : s1[base + 0];                         \
      float v1 = (kc < 2) ? s0[base + 1] : s1[base + 1];                         \
      float v2 = (kc < 2) ? s0[base + 2] : s1[base + 2];                         \
      float v3 = (kc < 2) ? s0[base + 3] : s1[base + 3];                         \
      float v4 = (kc < 2) ? s0[base + 4] : s1[base + 4];                         \
      float v5 = (kc < 2) ? s0[base + 5] : s1[base + 5];                         \
      float v6 = (kc < 2) ? s0[base + 6] : s1[base + 6];                         \
      float v7 = (kc < 2) ? s0[base + 7] : s1[base + 7];                         \
      unsigned pla = pk2(v0, v1), plb = pk2(v2, v3);                             \
      unsigned pha = pk2(v4, v5), phb = pk2(v6, v7);                             \
      unsigned ka = hi ? pha : pla, kb = hi ? phb : plb;                         \
      unsigned sa = hi ? pla : pha, sb = hi ? plb : phb;                         \
      unsigned ra = __shfl_xor(sa, 32), rb = __shfl_xor(sb, 32);                 \
      pa[kc] = hi ? mk8(ra, rb, ka, kb) : mk8(ka, kb, ra, rb);                   \
    }                                                                            \
  } while (0)

  STAGE_KV(0, 0);
  for (int kt = 0; kt <= qtA; ++kt) {
    const int cur = kt & 1;
    asm volatile("s_waitcnt vmcnt(0)" ::: "memory");
    __syncthreads();
    if (kt < qtA) STAGE_KV(cur ^ 1, (kt + 1) * 64);
    if (kt <= qt_w) {
      const bool edge = (kt == qt_w);
      bf16x8 pa1[4], pa2[4];
      __builtin_amdgcn_s_setprio(1);
      QK_MAT(K1s, q1f, pa1, l1);
      QK_MAT(K2s, q2f, pa2, l2);
#pragma unroll
      for (int n = 0; n < 4; ++n) {
        int vr = n * 32 + lc;
#pragma unroll
        for (int kc = 0; kc < 4; ++kc) {
          int g_ = (((kc * 2 + hi) ^ (lc & 7)) * 8);
          bf16x8 vf = *reinterpret_cast<const bf16x8*>(&Vs[cur][vr * 64 + g_]);
          o1[n] = mfma32(pa1[kc], vf, o1[n]);
          o2[n] = mfma32(pa2[kc], vf, o2[n]);
        }
      }
      __builtin_amdgcn_s_setprio(0);
    }
  }
#undef QK_MAT
#undef STAGE_KV

  // ---- epilogue: y = att1V - lam*att2V, per-row LN over 128, write bf16 ----
  l1 += __shfl_xor(l1, 32);
  l2 += __shfl_xor(l2, 32);
#pragma unroll
  for (int r = 0; r < 16; ++r) {
    int qr = (r & 3) + 8 * (r >> 2) + 4 * hi;
    float il1 = 1.0f / __shfl(l1, qr);
    float il2 = lam / __shfl(l2, qr);
    float y0 = o1[0][r] * il1 - o2[0][r] * il2;
    float y1 = o1[1][r] * il1 - o2[1][r] * il2;
    float y2 = o1[2][r] * il1 - o2[2][r] * il2;
    float y3 = o1[3][r] * il1 - o2[3][r] * il2;
    float sum = y0 + y1 + y2 + y3;
    float sq = y0 * y0 + y1 * y1 + y2 * y2 + y3 * y3;
#pragma unroll
    for (int mm = 16; mm >= 1; mm >>= 1) {
      sum += __shfl_xor(sum, mm);
      sq += __shfl_xor(sq, mm);
    }
    float mu = sum * (1.f / 128.f);
    float var = sq * (1.f / 128.f) - mu * mu;
    float rs = rsqrtf(var + 1e-5f) * ONE_MINUS_LI_F;
    bf16* orow = yln + (size_t)(b * T + qbase + qr) * 2048 + h * 128 + lc;
    orow[0]  = (bf16)((y0 - mu) * rs);
    orow[32] = (bf16)((y1 - mu) * rs);
    orow[64] = (bf16)((y2 - mu) * rs);
    orow[96] = (bf16)((y3 - mu) * rs);
  }
}

// ---------------- launch ----------------

extern "C" void kernel_launch(void* const* d_in, const int* in_sizes, int n_in,
                              void* d_out, int out_size, void* d_ws, size_t ws_size,
                              hipStream_t stream) {
  const float* x   = (const float*)d_in[0];
  const float* q1w = (const float*)d_in[1];
  const float* q2w = (const float*)d_in[2];
  const float* k1w = (const float*)d_in[3];
  const float* k2w = (const float*)d_in[4];
  const float* vw  = (const float*)d_in[5];
  const float* cw  = (const float*)d_in[6];
  const float* lq1 = (const float*)d_in[7];
  const float* lk1 = (const float*)d_in[8];
  const float* lq2 = (const float*)d_in[9];
  const float* lk2 = (const float*)d_in[10];
  float* out = (float*)d_out;

  char* ws = (char*)d_ws;
  bf16* qkv = (bf16*)(ws);                 // 50331648 B
  bf16* Wt  = (bf16*)(ws + 50331648);      // 12582912 B (dead after gemm1)
  bf16* xb  = (bf16*)(ws + 62914560);      // 8388608 B  (dead after gemm1)
  bf16* cwt = (bf16*)(ws + 71303168);      // 4194304 B
  bf16* yln = (bf16*)(ws + 75497472);      // 16777216 B
  bf16* Vt  = (bf16*)(ws + 50331648);      // 16777216 B, reuses Wt+xb region

  cvt_f32_bf16<<<4096, 256, 0, stream>>>(x, xb, 4096 * 1024 / 4);

  dim3 tb(32, 8);
  transpose_cvt<<<dim3(32, 32), tb, 0, stream>>>(q1w, Wt,               1024, 1024);
  transpose_cvt<<<dim3(32, 32), tb, 0, stream>>>(q2w, Wt + 1024 * 1024, 1024, 1024);
  transpose_cvt<<<dim3(32, 32), tb, 0, stream>>>(k1w, Wt + 2048 * 1024, 1024, 1024);
  transpose_cvt<<<dim3(32, 32), tb, 0, stream>>>(k2w, Wt + 3072 * 1024, 1024, 1024);
  transpose_cvt<<<dim3(64, 32), tb, 0, stream>>>(vw,  Wt + 4096 * 1024, 1024, 2048);
  transpose_cvt<<<dim3(32, 64), tb, 0, stream>>>(cw,  cwt,              2048, 1024);

  // qkv = x @ [q1|q2|k1|k2|v]
  gemm_bt<bf16><<<dim3(48, 32), 256, 0, stream>>>(xb, Wt, qkv, 4096, 6144, 1024);

  // Vt[bh][d][t]
  vtrans<<<dim3(32, 2, 32), 256, 0, stream>>>(qkv, Vt);

  // differential attention + per-head LN
  diff_attn<<<dim3(16, 32), 256, 0, stream>>>(qkv, Vt, lq1, lk1, lq2, lk2, yln);

  // out = yln @ c_w
  gemm_bt<float><<<dim3(8, 32), 256, 0, stream>>>(yln, cwt, out, 4096, 1024, 2048);
}

// Round 4
// 219.271 us; speedup vs baseline: 1.5323x; 1.5323x over previous
//
#include <hip/hip_runtime.h>
#include <cstdint>
#include <cstddef>

typedef __bf16 bf16;
typedef __bf16 bf16x8 __attribute__((ext_vector_type(8)));
typedef __bf16 bf16x4 __attribute__((ext_vector_type(4)));
typedef float f32x4 __attribute__((ext_vector_type(4)));

#define LAMBDA_INIT_F 0.5560582041556405f
#define ONE_MINUS_LI_F 0.4439417958443595f

static constexpr int T = 2048;
static constexpr int ROWQ = 6144;  // q1|q2|k1|k2|v(2048)
// P = exp(s/8 - 16) = exp2(s*C1 + C0)
#define C1_EXP2 0.18033688011116027f
#define C0_EXP2 -23.083120654223414f

__device__ __forceinline__ f32x4 mfma16(bf16x8 a, bf16x8 b, f32x4 c) {
  return __builtin_amdgcn_mfma_f32_16x16x32_bf16(a, b, c, 0, 0, 0);
}

__device__ __forceinline__ void gld16(const bf16* g, bf16* l) {
  __builtin_amdgcn_global_load_lds(
      (const __attribute__((address_space(1))) void*)g,
      (__attribute__((address_space(3))) void*)l, 16, 0, 0);
}

// ---------------- conversion kernels ----------------

__global__ void cvt_f32_bf16(const float* __restrict__ src, bf16* __restrict__ dst, int n4) {
  int i = blockIdx.x * blockDim.x + threadIdx.x;
  if (i < n4) {
    float4 v = reinterpret_cast<const float4*>(src)[i];
    bf16x4 o;
    o[0] = (bf16)v.x; o[1] = (bf16)v.y; o[2] = (bf16)v.z; o[3] = (bf16)v.w;
    reinterpret_cast<bf16x4*>(dst)[i] = o;
  }
}

// all weight transposes in ONE launch. [K][N] f32 -> [N][K] bf16
__global__ void transpose_all(const float* __restrict__ q1w, const float* __restrict__ q2w,
                              const float* __restrict__ k1w, const float* __restrict__ k2w,
                              const float* __restrict__ vw, const float* __restrict__ cw,
                              bf16* __restrict__ Wt, bf16* __restrict__ cwt) {
  __shared__ float t[32][33];
  const int id = blockIdx.x;
  const float* src;
  bf16* dst;
  int K, N, bx, by;
  if (id < 4096) {
    int wsel = id >> 10, r = id & 1023;
    src = (wsel == 0) ? q1w : (wsel == 1) ? q2w : (wsel == 2) ? k1w : k2w;
    dst = Wt + (size_t)wsel * 1024 * 1024;
    K = 1024; N = 1024; bx = r & 31; by = r >> 5;
  } else if (id < 6144) {
    int r = id - 4096;
    src = vw; dst = Wt + (size_t)4096 * 1024;
    K = 1024; N = 2048; bx = r & 63; by = r >> 6;
  } else {
    int r = id - 6144;
    src = cw; dst = cwt;
    K = 2048; N = 1024; bx = r & 31; by = r >> 5;
  }
  const int tx = threadIdx.x, ty = threadIdx.y;
  const int n0 = bx * 32, k0 = by * 32;
#pragma unroll
  for (int j = 0; j < 32; j += 8)
    t[ty + j][tx] = src[(size_t)(k0 + ty + j) * N + n0 + tx];
  __syncthreads();
#pragma unroll
  for (int j = 0; j < 32; j += 8)
    dst[(size_t)(n0 + ty + j) * K + k0 + tx] = (bf16)t[tx][ty + j];
}

// V part of qkv -> Vt[bh][d=128][t=2048]
__global__ void vtrans(const bf16* __restrict__ qkv, bf16* __restrict__ Vt) {
  __shared__ bf16 tile[64][72];
  const int tid = threadIdx.x;
  const int t0 = blockIdx.x * 64, dt = blockIdx.y, bh = blockIdx.z;
  const int b = bh >> 4, h = bh & 15;
#pragma unroll
  for (int i = 0; i < 2; ++i) {
    int S = tid + i * 256;
    int r = S >> 3, c = S & 7;
    *reinterpret_cast<bf16x8*>(&tile[r][c * 8]) =
        *reinterpret_cast<const bf16x8*>(
            &qkv[(size_t)(b * T + t0 + r) * ROWQ + 4096 + h * 128 + dt * 64 + c * 8]);
  }
  __syncthreads();
#pragma unroll
  for (int i = 0; i < 2; ++i) {
    int S = tid + i * 256;
    int dr = S >> 3, tc = S & 7;
    bf16x8 v;
#pragma unroll
    for (int j = 0; j < 8; ++j) v[j] = tile[tc * 8 + j][dr];
    *reinterpret_cast<bf16x8*>(
        &Vt[((size_t)bh * 128 + dt * 64 + dr) * 2048 + t0 + tc * 8]) = v;
  }
}

// ---------------- GEMM: A[M,K] x Bt[N,K] -> C[M,N], BK=64, dbuf, gload_lds ----------------
// BM=128: 4 waves in 2x2, wave tile 64x64. BM=64: 4 waves in 1x4, wave tile 64x32.

template <typename OutT, int BM>
__global__ __launch_bounds__(256, BM == 128 ? 2 : 3) void gemm_bt(
    const bf16* __restrict__ A, const bf16* __restrict__ Bt, OutT* __restrict__ C,
    int M, int N, int K) {
  constexpr int AIT = BM / 32;            // A-staging granule iters
  constexpr int AN = (BM == 128) ? 4 : 2; // n-frags per wave
  constexpr int WCN = (BM == 128) ? 64 : 32;
  __shared__ __align__(16) bf16 As[2][BM * 64];
  __shared__ __align__(16) bf16 Bs[2][128 * 64];
  const int tid = threadIdx.x;
  const int lane = tid & 63;
  const int wv = tid >> 6;
  const int wr = (BM == 128) ? (wv >> 1) : 0;
  const int wc = (BM == 128) ? (wv & 1) : wv;
  const int bm = blockIdx.y * BM, bn = blockIdx.x * 128;
  const int lr = lane & 15, lg = lane >> 4;

  f32x4 acc[4][AN] = {};
  const int KT = K >> 6;

#define STAGE_AB(buf, kk0)                                                      \
  do {                                                                          \
    _Pragma("unroll") for (int i_ = 0; i_ < 4; ++i_) {                          \
      int S_ = (i_ * 4 + wv) * 64 + lane;                                       \
      int rw_ = S_ >> 3;                                                        \
      int cg_ = (S_ & 7) ^ (rw_ & 7);                                           \
      if (i_ < AIT)                                                             \
        gld16(&A[(size_t)(bm + rw_) * K + (kk0) + cg_ * 8], &As[buf][(i_ * 4 + wv) * 512]); \
      gld16(&Bt[(size_t)(bn + rw_) * K + (kk0) + cg_ * 8], &Bs[buf][(i_ * 4 + wv) * 512]); \
    }                                                                           \
  } while (0)

  STAGE_AB(0, 0);
  for (int kt = 0; kt < KT; ++kt) {
    const int cur = kt & 1;
    asm volatile("s_waitcnt vmcnt(0)" ::: "memory");
    __syncthreads();
    if (kt + 1 < KT) STAGE_AB(cur ^ 1, (kt + 1) * 64);
#pragma unroll
    for (int kh = 0; kh < 2; ++kh) {
      bf16x8 af[4], bfr[AN];
#pragma unroll
      for (int m = 0; m < 4; ++m)
        af[m] = *reinterpret_cast<const bf16x8*>(
            &As[cur][(wr * 64 + m * 16 + lr) * 64 + (((kh * 4 + lg) ^ (lr & 7)) * 8)]);
#pragma unroll
      for (int n = 0; n < AN; ++n)
        bfr[n] = *reinterpret_cast<const bf16x8*>(
            &Bs[cur][(wc * WCN + n * 16 + lr) * 64 + (((kh * 4 + lg) ^ (lr & 7)) * 8)]);
#pragma unroll
      for (int m = 0; m < 4; ++m)
#pragma unroll
        for (int n = 0; n < AN; ++n)
          acc[m][n] = mfma16(af[m], bfr[n], acc[m][n]);
    }
  }
#undef STAGE_AB

#pragma unroll
  for (int m = 0; m < 4; ++m)
#pragma unroll
    for (int n = 0; n < AN; ++n)
#pragma unroll
      for (int r = 0; r < 4; ++r) {
        int row = bm + wr * 64 + m * 16 + lg * 4 + r;
        int col = bn + wc * WCN + n * 16 + lr;
        C[(size_t)row * N + col] = (OutT)acc[m][n][r];
      }
}

// ---------------- differential flash attention + per-head LayerNorm ----------------
// grid (16, 32): block handles q-tiles {31-u (A), u (B)}; u chosen so co-resident
// block pairs (bid, bid+256) have complementary loop lengths (49 steps/CU).

__global__ __launch_bounds__(256, 2) void diff_attn(const bf16* __restrict__ qkv,
                                                    const bf16* __restrict__ Vtg,
                                                    const float* __restrict__ lq1,
                                                    const float* __restrict__ lk1,
                                                    const float* __restrict__ lq2,
                                                    const float* __restrict__ lk2,
                                                    bf16* __restrict__ yln) {
  constexpr int LDP = 72;
  __shared__ __align__(16) bf16 K1s[2][64 * 64];
  __shared__ __align__(16) bf16 K2s[2][64 * 64];
  __shared__ __align__(16) bf16 Vs[2][128 * 64];
  __shared__ __align__(16) bf16 Ps[4][16 * LDP];

  const int x = blockIdx.x;
  const int bh = blockIdx.y;
  const int b = bh >> 4, h = bh & 15;
  const int tid = threadIdx.x, lane = tid & 63, wv = tid >> 6;
  const int lr = lane & 15, lg = lane >> 4;
  const int u = b ? x : 15 - x;
  const int qtA = 31 - u;  // big tile
  const int qtB = u;       // small tile

  const int q1c = h * 64;
  const int q2c = 1024 + h * 64;
  const int k1c = 2048 + h * 64;
  const int k2c = 3072 + h * 64;

  // lambda
  float a1 = lq1[h * 64 + lane] * lk1[h * 64 + lane];
  float a2 = lq2[h * 64 + lane] * lk2[h * 64 + lane];
#pragma unroll
  for (int m = 32; m >= 1; m >>= 1) {
    a1 += __shfl_xor(a1, m);
    a2 += __shfl_xor(a2, m);
  }
  const float lam = __expf(a1) - __expf(a2) + LAMBDA_INIT_F;

  bf16x8 onesf;
#pragma unroll
  for (int j = 0; j < 8; ++j) onesf[j] = (bf16)1.0f;

  // Q fragments for both tiles
  bf16x8 q1fA[2], q2fA[2], q1fB[2], q2fB[2];
  {
    const bf16* qa = qkv + (size_t)(b * T + qtA * 64 + wv * 16 + lr) * ROWQ;
    const bf16* qb = qkv + (size_t)(b * T + qtB * 64 + wv * 16 + lr) * ROWQ;
#pragma unroll
    for (int kc = 0; kc < 2; ++kc) {
      q1fA[kc] = *reinterpret_cast<const bf16x8*>(qa + q1c + kc * 32 + lg * 8);
      q2fA[kc] = *reinterpret_cast<const bf16x8*>(qa + q2c + kc * 32 + lg * 8);
      q1fB[kc] = *reinterpret_cast<const bf16x8*>(qb + q1c + kc * 32 + lg * 8);
      q2fB[kc] = *reinterpret_cast<const bf16x8*>(qb + q2c + kc * 32 + lg * 8);
    }
  }

  f32x4 o1A[8] = {}, o2A[8] = {}, o1B[8] = {}, o2B[8] = {};
  f32x4 lA1 = {}, lA2 = {}, lB1 = {}, lB2 = {};

#define STAGE_KV(buf, tt0)                                                       \
  do {                                                                           \
    const bf16* kb_ = qkv + (size_t)(b * T + (tt0)) * ROWQ;                      \
    _Pragma("unroll") for (int i_ = 0; i_ < 2; ++i_) {                           \
      int S_ = (i_ * 4 + wv) * 64 + lane;                                        \
      int rw_ = S_ >> 3;                                                         \
      int cg_ = (S_ & 7) ^ (rw_ & 7);                                            \
      gld16(kb_ + (size_t)rw_ * ROWQ + k1c + cg_ * 8, &K1s[buf][(i_ * 4 + wv) * 512]); \
      gld16(kb_ + (size_t)rw_ * ROWQ + k2c + cg_ * 8, &K2s[buf][(i_ * 4 + wv) * 512]); \
    }                                                                            \
    _Pragma("unroll") for (int i_ = 0; i_ < 4; ++i_) {                           \
      int S_ = (i_ * 4 + wv) * 64 + lane;                                        \
      int dd_ = S_ >> 3;                                                         \
      int cg_ = (S_ & 7) ^ (dd_ & 7);                                            \
      gld16(Vtg + ((size_t)bh * 128 + dd_) * 2048 + (tt0) + cg_ * 8,             \
            &Vs[buf][(i_ * 4 + wv) * 512]);                                      \
    }                                                                            \
  } while (0)

#define ATT_STEP(q1f_, q2f_, o1_, o2_, l1_, l2_, edge_)                          \
  do {                                                                           \
    f32x4 s1_[4] = {}, s2_[4] = {};                                              \
    _Pragma("unroll") for (int n_ = 0; n_ < 4; ++n_) {                           \
      int krow_ = n_ * 16 + lr;                                                  \
      _Pragma("unroll") for (int kc_ = 0; kc_ < 2; ++kc_) {                      \
        bf16x8 kf1_ = *reinterpret_cast<const bf16x8*>(                          \
            &K1s[cur][krow_ * 64 + (((kc_ * 4 + lg) ^ (lr & 7)) * 8)]);          \
        bf16x8 kf2_ = *reinterpret_cast<const bf16x8*>(                          \
            &K2s[cur][krow_ * 64 + (((kc_ * 4 + lg) ^ (lr & 7)) * 8)]);          \
        s1_[n_] = mfma16(q1f_[kc_], kf1_, s1_[n_]);                              \
        s2_[n_] = mfma16(q2f_[kc_], kf2_, s2_[n_]);                              \
      }                                                                          \
    }                                                                            \
    _Pragma("unroll") for (int n_ = 0; n_ < 4; ++n_)                             \
    _Pragma("unroll") for (int r_ = 0; r_ < 4; ++r_) {                           \
      float e1_ = fmaf(s1_[n_][r_], C1_EXP2, C0_EXP2);                           \
      float e2_ = fmaf(s2_[n_][r_], C1_EXP2, C0_EXP2);                           \
      if (edge_) {                                                               \
        int qq_ = wv * 16 + lg * 4 + r_;                                         \
        int kk_ = n_ * 16 + lr;                                                  \
        if (kk_ > qq_) { e1_ = -10000.f; e2_ = -10000.f; }                       \
      }                                                                          \
      s1_[n_][r_] = exp2f(e1_);                                                  \
      s2_[n_][r_] = exp2f(e2_);                                                  \
    }                                                                            \
    bf16* Pw_ = &Ps[wv][0];                                                      \
    bf16x8 pa1_[2], pa2_[2];                                                     \
    _Pragma("unroll") for (int n_ = 0; n_ < 4; ++n_)                             \
    _Pragma("unroll") for (int r_ = 0; r_ < 4; ++r_)                             \
        Pw_[(lg * 4 + r_) * LDP + n_ * 16 + lr] = (bf16)s1_[n_][r_];             \
    _Pragma("unroll") for (int kc_ = 0; kc_ < 2; ++kc_)                          \
        pa1_[kc_] = *reinterpret_cast<const bf16x8*>(&Pw_[lr * LDP + kc_ * 32 + lg * 8]); \
    _Pragma("unroll") for (int n_ = 0; n_ < 4; ++n_)                             \
    _Pragma("unroll") for (int r_ = 0; r_ < 4; ++r_)                             \
        Pw_[(lg * 4 + r_) * LDP + n_ * 16 + lr] = (bf16)s2_[n_][r_];             \
    _Pragma("unroll") for (int kc_ = 0; kc_ < 2; ++kc_)                          \
        pa2_[kc_] = *reinterpret_cast<const bf16x8*>(&Pw_[lr * LDP + kc_ * 32 + lg * 8]); \
    _Pragma("unroll") for (int kc_ = 0; kc_ < 2; ++kc_) {                        \
      l1_ = mfma16(pa1_[kc_], onesf, l1_);                                       \
      l2_ = mfma16(pa2_[kc_], onesf, l2_);                                       \
      _Pragma("unroll") for (int nf_ = 0; nf_ < 8; ++nf_) {                      \
        int dd_ = nf_ * 16 + lr;                                                 \
        bf16x8 vb_ = *reinterpret_cast<const bf16x8*>(                           \
            &Vs[cur][dd_ * 64 + (((kc_ * 4 + lg) ^ (lr & 7)) * 8)]);             \
        o1_[nf_] = mfma16(pa1_[kc_], vb_, o1_[nf_]);                             \
        o2_[nf_] = mfma16(pa2_[kc_], vb_, o2_[nf_]);                             \
      }                                                                          \
    }                                                                            \
  } while (0)

  STAGE_KV(0, 0);
  for (int kt = 0; kt <= qtA; ++kt) {
    const int cur = kt & 1;
    asm volatile("s_waitcnt vmcnt(0)" ::: "memory");
    __syncthreads();
    if (kt < qtA) STAGE_KV(cur ^ 1, (kt + 1) * 64);
    __builtin_amdgcn_s_setprio(1);
    ATT_STEP(q1fA, q2fA, o1A, o2A, lA1, lA2, (kt == qtA));
    if (kt <= qtB) ATT_STEP(q1fB, q2fB, o1B, o2B, lB1, lB2, (kt == qtB));
    __builtin_amdgcn_s_setprio(0);
  }
#undef ATT_STEP
#undef STAGE_KV

#define ATT_EPI(o1_, o2_, l1_, l2_, qt_)                                         \
  do {                                                                           \
    float sum_[4] = {}, sq_[4] = {};                                             \
    float i1_[4], i2_[4];                                                        \
    _Pragma("unroll") for (int r_ = 0; r_ < 4; ++r_) {                           \
      i1_[r_] = 1.f / l1_[r_];                                                   \
      i2_[r_] = lam / l2_[r_];                                                   \
    }                                                                            \
    _Pragma("unroll") for (int nf_ = 0; nf_ < 8; ++nf_)                          \
    _Pragma("unroll") for (int r_ = 0; r_ < 4; ++r_) {                           \
      float v_ = o1_[nf_][r_] * i1_[r_] - o2_[nf_][r_] * i2_[r_];                \
      o1_[nf_][r_] = v_;                                                         \
      sum_[r_] += v_;                                                            \
      sq_[r_] += v_ * v_;                                                        \
    }                                                                            \
    _Pragma("unroll") for (int r_ = 0; r_ < 4; ++r_)                             \
    _Pragma("unroll") for (int mm_ = 8; mm_ >= 1; mm_ >>= 1) {                   \
      sum_[r_] += __shfl_xor(sum_[r_], mm_);                                     \
      sq_[r_] += __shfl_xor(sq_[r_], mm_);                                       \
    }                                                                            \
    _Pragma("unroll") for (int r_ = 0; r_ < 4; ++r_) {                           \
      float mu_ = sum_[r_] * (1.f / 128.f);                                      \
      float var_ = sq_[r_] * (1.f / 128.f) - mu_ * mu_;                          \
      float rs_ = rsqrtf(var_ + 1e-5f) * ONE_MINUS_LI_F;                         \
      int row_ = b * T + (qt_)*64 + wv * 16 + lg * 4 + r_;                       \
      bf16* orow_ = yln + (size_t)row_ * 2048 + h * 128;                         \
      _Pragma("unroll") for (int nf_ = 0; nf_ < 8; ++nf_)                        \
          orow_[nf_ * 16 + lr] = (bf16)((o1_[nf_][r_] - mu_) * rs_);             \
    }                                                                            \
  } while (0)

  ATT_EPI(o1A, o2A, lA1, lA2, qtA);
  ATT_EPI(o1B, o2B, lB1, lB2, qtB);
#undef ATT_EPI
}

// ---------------- launch ----------------

extern "C" void kernel_launch(void* const* d_in, const int* in_sizes, int n_in,
                              void* d_out, int out_size, void* d_ws, size_t ws_size,
                              hipStream_t stream) {
  const float* x   = (const float*)d_in[0];
  const float* q1w = (const float*)d_in[1];
  const float* q2w = (const float*)d_in[2];
  const float* k1w = (const float*)d_in[3];
  const float* k2w = (const float*)d_in[4];
  const float* vw  = (const float*)d_in[5];
  const float* cw  = (const float*)d_in[6];
  const float* lq1 = (const float*)d_in[7];
  const float* lk1 = (const float*)d_in[8];
  const float* lq2 = (const float*)d_in[9];
  const float* lk2 = (const float*)d_in[10];
  float* out = (float*)d_out;

  char* ws = (char*)d_ws;
  bf16* qkv = (bf16*)(ws);                 // 50331648 B
  bf16* Wt  = (bf16*)(ws + 50331648);      // 12582912 B (dead after gemm1)
  bf16* xb  = (bf16*)(ws + 62914560);      // 8388608 B  (dead after gemm1)
  bf16* cwt = (bf16*)(ws + 71303168);      // 4194304 B
  bf16* yln = (bf16*)(ws + 75497472);      // 16777216 B
  bf16* Vt  = (bf16*)(ws + 50331648);      // 16777216 B, reuses Wt+xb region

  cvt_f32_bf16<<<4096, 256, 0, stream>>>(x, xb, 4096 * 1024 / 4);

  transpose_all<<<8192, dim3(32, 8), 0, stream>>>(q1w, q2w, k1w, k2w, vw, cw, Wt, cwt);

  // qkv = x @ [q1|q2|k1|k2|v]
  gemm_bt<bf16, 128><<<dim3(48, 32), 256, 0, stream>>>(xb, Wt, qkv, 4096, 6144, 1024);

  // Vt[bh][d][t]
  vtrans<<<dim3(32, 2, 32), 256, 0, stream>>>(qkv, Vt);

  // differential attention + per-head LN
  diff_attn<<<dim3(16, 32), 256, 0, stream>>>(qkv, Vt, lq1, lk1, lq2, lk2, yln);

  // out = yln @ c_w  (BM=64 -> 512 blocks, 2+ blocks/CU)
  gemm_bt<float, 64><<<dim3(8, 64), 256, 0, stream>>>(yln, cwt, out, 4096, 1024, 2048);
}